// Round 1
// baseline (571.386 us; speedup 1.0000x reference)
//
#include <hip/hip_runtime.h>
#include <cstdint>
#include <cstddef>

typedef __bf16 bf16_t;
typedef __attribute__((ext_vector_type(8))) __bf16 bf16x8;
typedef __attribute__((ext_vector_type(4))) __bf16 bf16x4;
typedef __attribute__((ext_vector_type(4))) float floatx4;

#define NB 32
#define NW 168
#define NM 2048
#define NHID 128
#define NBW (NB * NW)  // 5376

#define GLOAD_LDS16(g, l)                                          \
  __builtin_amdgcn_global_load_lds(                                \
      (const __attribute__((address_space(1))) void*)(g),          \
      (__attribute__((address_space(3))) void*)(l), 16, 0, 0)

// elementwise fp32 -> bf16 cast, n4 = n/4
__global__ void cast_bf16_kernel(const float* __restrict__ in, bf16_t* __restrict__ out, int n4) {
  int stride = gridDim.x * blockDim.x;
  for (int i = blockIdx.x * blockDim.x + threadIdx.x; i < n4; i += stride) {
    float4 v = ((const float4*)in)[i];
    bf16x4 o = {(bf16_t)v.x, (bf16_t)v.y, (bf16_t)v.z, (bf16_t)v.w};
    ((bf16x4*)out)[i] = o;
  }
}

// Fused x prep: read x [(bw)][m] fp32 once; write Xb [(bw)][m] bf16 (cast) and
// XT [m][(bw)] bf16 (transpose). 64x64 tiles.
__global__ void prep_x_kernel(const float* __restrict__ x, bf16_t* __restrict__ Xb,
                              bf16_t* __restrict__ XT) {
  __shared__ float tile[64][65];
  const int R = NBW, C = NM;
  int r0 = blockIdx.y * 64, c0 = blockIdx.x * 64;
  int t = threadIdx.x;
  int tr = t >> 4, tc4 = (t & 15) * 4;
#pragma unroll
  for (int p = 0; p < 4; ++p) {
    int row = p * 16 + tr;
    float4 v = *(const float4*)(x + (size_t)(r0 + row) * C + c0 + tc4);
    tile[row][tc4 + 0] = v.x;
    tile[row][tc4 + 1] = v.y;
    tile[row][tc4 + 2] = v.z;
    tile[row][tc4 + 3] = v.w;
    bf16x4 o = {(bf16_t)v.x, (bf16_t)v.y, (bf16_t)v.z, (bf16_t)v.w};
    *(bf16x4*)(Xb + (size_t)(r0 + row) * C + c0 + tc4) = o;
  }
  __syncthreads();
#pragma unroll
  for (int p = 0; p < 4; ++p) {
    int c = p * 16 + tr;
    bf16x4 o = {(bf16_t)tile[tc4 + 0][c], (bf16_t)tile[tc4 + 1][c],
                (bf16_t)tile[tc4 + 2][c], (bf16_t)tile[tc4 + 3][c]};
    *(bf16x4*)(XT + (size_t)(c0 + c) * R + r0 + tc4) = o;
  }
}

// ---------------------------------------------------------------------------
// 256x256 8-phase NT GEMM (HK-style schedule, plain HIP):
//   C[m,n] = sum_k A[m,k]*Bt[n,k]
// 512 threads = 8 waves (2M x 4N), per-wave output 128x64. BK=64, double-
// buffered: buf0 = even K-tiles, buf1 = odd K-tiles. Each K-tile split into
// two K-halves (ks=0/1) of [256 rows][32 k]; one half-stage (2x
// global_load_lds dwordx4 per thread) issued per phase; counted vmcnt(4) only
// at phases 4 and 8 (loads stay in flight across barriers).
// LDS swizzle: linear global_load_lds dest + inverse-swizzled GLOBAL source
// (chunk c stored from global chunk c^(row&3)); ds_read applies the same XOR
// -> 64 lanes of a fragment read hit 64 distinct 16B slots (conflict-free).
// Epilogue also writes Ct[n][m] (transposed, bf16x4) for the MLP input.
// ---------------------------------------------------------------------------
#define STAGE2(gbase, ld, t, ks, ldsbase)                                        \
  do {                                                                           \
    const bf16_t* _g = (gbase) + (size_t)(t) * 64 + (ks) * 32;                   \
    GLOAD_LDS16(_g, lds + (ldsbase) + (ks) * 8192 + wv * 512);                   \
    GLOAD_LDS16(_g + (size_t)128 * (ld),                                         \
                lds + (ldsbase) + (ks) * 8192 + 4096 + wv * 512);                \
  } while (0)

#define VM4 asm volatile("s_waitcnt vmcnt(4)" ::: "memory")

#define PHASE(bufoff, ks, mh, READB, STG, WAIT)                                  \
  do {                                                                           \
    if (READB) {                                                                 \
      _Pragma("unroll") for (int ni = 0; ni < 4; ++ni)                           \
          bfr[ni] = *(const bf16x8*)(pB + (bufoff) + (ks) * 8192 + ni * 512);    \
    }                                                                            \
    _Pragma("unroll") for (int mi = 0; mi < 4; ++mi)                             \
        afr[mi] =                                                                \
            *(const bf16x8*)(pA + (bufoff) + (ks) * 8192 + ((mh) * 4 + mi) * 512); \
    STG;                                                                         \
    WAIT;                                                                        \
    __builtin_amdgcn_s_barrier();                                                \
    asm volatile("s_waitcnt lgkmcnt(0)" ::: "memory");                           \
    __builtin_amdgcn_sched_barrier(0);                                           \
    __builtin_amdgcn_s_setprio(1);                                               \
    _Pragma("unroll") for (int mi = 0; mi < 4; ++mi)                             \
        _Pragma("unroll") for (int ni = 0; ni < 4; ++ni)                         \
            acc[(mh) * 4 + mi][ni] = __builtin_amdgcn_mfma_f32_16x16x32_bf16(    \
                afr[mi], bfr[ni], acc[(mh) * 4 + mi][ni], 0, 0, 0);              \
    __builtin_amdgcn_s_setprio(0);                                               \
    __builtin_amdgcn_s_barrier();                                                \
  } while (0)

__global__ __launch_bounds__(512, 2) void gemm_nt_kernel(
    const bf16_t* __restrict__ A, const bf16_t* __restrict__ Bt,
    bf16_t* __restrict__ C, bf16_t* __restrict__ Ct,
    int K, int lda, int ldb, int ldc, int ldct, int write_c) {
  // LDS elem map (bf16): buf b: A at b*32768 + ks*8192, B at b*32768+16384+ks*8192
  __shared__ bf16_t lds[65536];  // 128 KiB
  const int tid = threadIdx.x;
  const int m0 = blockIdx.y * 256, n0 = blockIdx.x * 256;
  const int lane = tid & 63, wv = tid >> 6;
  const int wm = wv >> 2, wn = wv & 3;
  const int quad = lane >> 4, l15 = lane & 15;

  // staging source (per thread): rows srow and srow+128 of the 256-row half,
  // chunk pre-swizzled so the linear LDS write lands swizzled data.
  const int srow = tid >> 2;
  const int scsw = (tid & 3) ^ (srow & 3);
  const bf16_t* aS = A + (size_t)(m0 + srow) * lda + scsw * 8;
  const bf16_t* bS = Bt + (size_t)(n0 + srow) * ldb + scsw * 8;

  // fragment read base (elems): row*32 + swizzled chunk (row&3 == l15&3)
  const int fsw = (quad ^ (l15 & 3)) * 8;
  const bf16_t* pA = lds + (size_t)(wm * 128 + l15) * 32 + fsw;
  const bf16_t* pB = lds + 16384 + (size_t)(wn * 64 + l15) * 32 + fsw;

  floatx4 zero4 = {0.f, 0.f, 0.f, 0.f};
  floatx4 acc[8][4];
#pragma unroll
  for (int mi = 0; mi < 8; ++mi)
#pragma unroll
    for (int ni = 0; ni < 4; ++ni) acc[mi][ni] = zero4;

  // prologue: tile0 (all 4 halves, buf0) + tile1 ks0 (buf1); leave tile1-ks0
  // in flight (vmcnt(4)) -- tile0 fully landed after the barrier.
  STAGE2(aS, lda, 0, 0, 0);
  STAGE2(bS, ldb, 0, 0, 16384);
  STAGE2(aS, lda, 0, 1, 0);
  STAGE2(bS, ldb, 0, 1, 16384);
  STAGE2(aS, lda, 1, 0, 32768);
  STAGE2(bS, ldb, 1, 0, 49152);
  VM4;
  __builtin_amdgcn_s_barrier();

  bf16x8 afr[4], bfr[4];
  const int nt = K >> 6;    // K-tiles
  const int nit = K >> 7;   // iterations (2 K-tiles each)
#pragma unroll 1
  for (int i = 0; i < nit; ++i) {
    const int t1 = 2 * i + 1;
    const int t2 = (t1 + 1 < nt) ? t1 + 1 : 0;  // clamp: keep vmcnt counts uniform
    const int t3 = (t1 + 2 < nt) ? t1 + 2 : 0;
    // phases 1-4: compute buf0 (tile 2i); phases 5-8: compute buf1 (tile 2i+1)
    PHASE(0,     0, 0, 1, STAGE2(aS, lda, t1, 1, 32768), (void)0);
    PHASE(0,     0, 1, 0, STAGE2(bS, ldb, t1, 1, 49152), (void)0);
    PHASE(0,     1, 0, 1, STAGE2(aS, lda, t2, 0, 0),     (void)0);
    PHASE(0,     1, 1, 0, STAGE2(bS, ldb, t2, 0, 16384), VM4);
    PHASE(32768, 0, 0, 1, STAGE2(aS, lda, t2, 1, 0),     (void)0);
    PHASE(32768, 0, 1, 0, STAGE2(bS, ldb, t2, 1, 16384), (void)0);
    PHASE(32768, 1, 0, 1, STAGE2(aS, lda, t3, 0, 32768), (void)0);
    PHASE(32768, 1, 1, 0, STAGE2(bS, ldb, t3, 0, 49152), VM4);
  }
  asm volatile("s_waitcnt vmcnt(0)" ::: "memory");

  // epilogue: C rows m0+wm*128+mi*16+quad*4+r, cols n0+wn*64+ni*16+l15
#pragma unroll
  for (int mi = 0; mi < 8; ++mi) {
#pragma unroll
    for (int ni = 0; ni < 4; ++ni) {
      int col = n0 + wn * 64 + ni * 16 + l15;
      int rowb = m0 + wm * 128 + mi * 16 + quad * 4;
      bf16x4 tv;
#pragma unroll
      for (int r = 0; r < 4; ++r) tv[r] = (bf16_t)acc[mi][ni][r];
      *(bf16x4*)(Ct + (size_t)col * ldct + rowb) = tv;
      if (write_c) {
#pragma unroll
        for (int r = 0; r < 4; ++r)
          C[(size_t)(rowb + r) * ldc + col] = tv[r];
      }
    }
  }
}

// Fused per-hop MLP + score. Rows r = m*32+b (128 per block); T row (m,b) at
// m*NBW + b*NW in XT. K=168 padded to 192: W1 staged once into LDS in [kc][h]
// chunk layout (kc 21..23 zeroed, so no A-side predication needed: A garbage
// times B zero contributes 0). A fragments read directly from global.
// score = sum_h relu(H+b1)*W2 + b2 -> out[b*NM+m]
__global__ void mlp_score_kernel(const bf16_t* __restrict__ T, const bf16_t* __restrict__ W1b,
                                 const float* __restrict__ b1, const float* __restrict__ W2,
                                 const float* __restrict__ b2, float* __restrict__ out,
                                 int hop, int accumulate) {
  __shared__ bf16_t Bs[24 * 128 * 8];  // 48 KB: chunk (kc,h_pos) at (kc*128+h_pos)*8
  __shared__ float sred[4][64];
  const bf16_t* Wh = W1b + (size_t)hop * NHID * NW;
  const float* b1h = b1 + hop * NHID;
  const float* w2h = W2 + hop * NHID;
  int tid = threadIdx.x;
  int r0 = blockIdx.x * 128;
  int lane = tid & 63, wv = tid >> 6;
  int wm = wv >> 1, wn = wv & 1;
  int quad = lane >> 4, l15 = lane & 15;

  // zero the pad chunks [2688, 3072) = kc 21..23
  for (int c = 2688 + tid; c < 3072; c += 256) {
    int4 z = {0, 0, 0, 0};
    *(int4*)(Bs + (size_t)c * 8) = z;
  }
  // stage 2688 valid chunks; LDS pos c -> kc=c>>7, h = (c&127) ^ ((kc&3)<<2)
  for (int i = 0; i < 11; ++i) {
    int c = i * 256 + tid;
    if (c < 2688) {  // 2688 = 42 full waves: no partial-wave exec masks
      int kc = c >> 7;
      int h = (c & 127) ^ ((kc & 3) << 2);
      GLOAD_LDS16(Wh + (size_t)h * NW + kc * 8, Bs + (size_t)(i * 256 + wv * 64) * 8);
    }
  }

  // A row pointers (per mi): row index R = r0 + wm*64 + mi*16 + l15
  const bf16_t* arow[4];
#pragma unroll
  for (int mi = 0; mi < 4; ++mi) {
    int R = r0 + wm * 64 + mi * 16 + l15;
    arow[mi] = T + (size_t)(R >> 5) * NBW + (size_t)(R & 31) * NW + quad * 8;
  }

  floatx4 zero4 = {0.f, 0.f, 0.f, 0.f};
  floatx4 acc[4][4];
#pragma unroll
  for (int mi = 0; mi < 4; ++mi)
#pragma unroll
    for (int ni = 0; ni < 4; ++ni) acc[mi][ni] = zero4;

  __syncthreads();  // staging (incl. async loads) complete

#pragma unroll
  for (int kb = 0; kb < 192; kb += 32) {
    int kc = (kb >> 3) + quad;
    bf16x8 af[4], bf[4];
#pragma unroll
    for (int mi = 0; mi < 4; ++mi)
      af[mi] = *(const bf16x8*)(arow[mi] + kb);  // k>=168 reads garbage; B pad=0
#pragma unroll
    for (int ni = 0; ni < 4; ++ni) {
      int hpos = (wn * 64 + ni * 16 + l15) ^ ((kc & 3) << 2);
      bf[ni] = *(const bf16x8*)(Bs + (size_t)(kc * 128 + hpos) * 8);
    }
#pragma unroll
    for (int mi = 0; mi < 4; ++mi)
#pragma unroll
      for (int ni = 0; ni < 4; ++ni)
        acc[mi][ni] = __builtin_amdgcn_mfma_f32_16x16x32_bf16(af[mi], bf[ni], acc[mi][ni], 0, 0, 0);
  }

  // epilogue: relu(H + b1) dot W2 per row
  float part[4][4];
#pragma unroll
  for (int mi = 0; mi < 4; ++mi)
#pragma unroll
    for (int r = 0; r < 4; ++r) part[mi][r] = 0.f;
#pragma unroll
  for (int ni = 0; ni < 4; ++ni) {
    int col = wn * 64 + ni * 16 + l15;
    float b1v = b1h[col];
    float w2v = w2h[col];
#pragma unroll
    for (int mi = 0; mi < 4; ++mi)
#pragma unroll
      for (int r = 0; r < 4; ++r) {
        float h = acc[mi][ni][r] + b1v;
        h = h > 0.f ? h : 0.f;
        part[mi][r] += h * w2v;
      }
  }
#pragma unroll
  for (int off = 1; off < 16; off <<= 1)
#pragma unroll
    for (int mi = 0; mi < 4; ++mi)
#pragma unroll
      for (int r = 0; r < 4; ++r) part[mi][r] += __shfl_xor(part[mi][r], off);
  if (l15 == 0) {
#pragma unroll
    for (int mi = 0; mi < 4; ++mi)
#pragma unroll
      for (int r = 0; r < 4; ++r) sred[wv][mi * 16 + quad * 4 + r] = part[mi][r];
  }
  __syncthreads();
  if (tid < 128) {
    int half = tid >> 6;
    int lr = tid & 63;
    float v = sred[half * 2][lr] + sred[half * 2 + 1][lr] + b2[hop];
    int R = r0 + half * 64 + lr;
    int idx = (R & 31) * NM + (R >> 5);  // out[b*M + m]
    if (accumulate)
      out[idx] += v;
    else
      out[idx] = v;
  }
}

extern "C" void kernel_launch(void* const* d_in, const int* in_sizes, int n_in,
                              void* d_out, int out_size, void* d_ws, size_t ws_size,
                              hipStream_t stream) {
  const float* x = (const float*)d_in[0];
  const float* L = (const float*)d_in[1];
  const float* W1 = (const float*)d_in[2];
  const float* b1 = (const float*)d_in[3];
  const float* W2 = (const float*)d_in[4];
  const float* b2 = (const float*)d_in[5];
  float* out = (float*)d_out;

  char* ws = (char*)d_ws;
  size_t off = 0;
  auto walloc = [&](size_t bytes) -> void* {
    off = (off + 255) & ~(size_t)255;
    void* p = ws + off;
    off += bytes;
    return p;
  };
  bf16_t* Xb = (bf16_t*)walloc((size_t)NBW * NM * 2);   // Tt_0 = x cast: [(b,w)][m]
  bf16_t* XT = (bf16_t*)walloc((size_t)NM * NBW * 2);   // [m][(b,w)] MLP input (per hop)
  bf16_t* Lb = (bf16_t*)walloc((size_t)NM * NM * 2);    // L bf16 (NT B-operand)
  bf16_t* W1b = (bf16_t*)walloc((size_t)7 * NHID * NW * 2);
  bf16_t* Ta = (bf16_t*)walloc((size_t)NBW * NM * 2);   // ping-pong partner of Xb
  (void)ws_size; (void)in_sizes; (void)n_in; (void)out_size;

  prep_x_kernel<<<dim3(NM / 64, NBW / 64), dim3(256), 0, stream>>>(x, Xb, XT);
  cast_bf16_kernel<<<dim3(1024), dim3(256), 0, stream>>>(L, Lb, NM * NM / 4);
  cast_bf16_kernel<<<dim3(64), dim3(256), 0, stream>>>(W1, W1b, 7 * NHID * NW / 4);

  // hop 0: identity propagation
  mlp_score_kernel<<<dim3(NM * NB / 128), dim3(256), 0, stream>>>(XT, W1b, b1, W2, b2, out, 0, 0);

  // T-chain: Tt_i[(bw)][m] = sum_k Tt_{i-1}[(bw)][k] * L[m][k]   (NT, Bt = Lb)
  // Epilogue writes both Tt_i (for next hop) and XT = Tt_i^T (for the MLP).
  bf16_t* src = Xb;
  bf16_t* dst = Ta;
  for (int i = 1; i <= 6; ++i) {
    gemm_nt_kernel<<<dim3(NM / 256, NBW / 256), dim3(512), 0, stream>>>(
        src, Lb, dst, XT, NM, NM, NM, NM, NBW, (i < 6) ? 1 : 0);
    mlp_score_kernel<<<dim3(NM * NB / 128), dim3(256), 0, stream>>>(XT, W1b, b1, W2, b2, out, i, 1);
    bf16_t* t = src; src = dst; dst = t;
  }
}

// Round 2
// 482.381 us; speedup vs baseline: 1.1845x; 1.1845x over previous
//
#include <hip/hip_runtime.h>
#include <cstdint>
#include <cstddef>

typedef __bf16 bf16_t;
typedef __attribute__((ext_vector_type(8))) __bf16 bf16x8;
typedef __attribute__((ext_vector_type(4))) __bf16 bf16x4;
typedef __attribute__((ext_vector_type(4))) float floatx4;

#define NB 32
#define NW 168
#define NM 2048
#define NHID 128
#define NBW (NB * NW)  // 5376
#define NGEMM 168      // 21 m-tiles x 8 n-tiles of 256^2
#define NMLPB 256      // 256 fused blocks x 2 halves = 512 row-blocks of 128

#define GLOAD_LDS16(g, l)                                          \
  __builtin_amdgcn_global_load_lds(                                \
      (const __attribute__((address_space(1))) void*)(g),          \
      (__attribute__((address_space(3))) void*)(l), 16, 0, 0)

// elementwise fp32 -> bf16 cast, n4 = n/4
__global__ void cast_bf16_kernel(const float* __restrict__ in, bf16_t* __restrict__ out, int n4) {
  int stride = gridDim.x * blockDim.x;
  for (int i = blockIdx.x * blockDim.x + threadIdx.x; i < n4; i += stride) {
    float4 v = ((const float4*)in)[i];
    bf16x4 o = {(bf16_t)v.x, (bf16_t)v.y, (bf16_t)v.z, (bf16_t)v.w};
    ((bf16x4*)out)[i] = o;
  }
}

// Fused x prep: read x [(bw)][m] fp32 once; write Xb [(bw)][m] bf16 (cast) and
// XT [m][(bw)] bf16 (transpose). 64x64 tiles.
__global__ void prep_x_kernel(const float* __restrict__ x, bf16_t* __restrict__ Xb,
                              bf16_t* __restrict__ XT) {
  __shared__ float tile[64][65];
  const int R = NBW, C = NM;
  int r0 = blockIdx.y * 64, c0 = blockIdx.x * 64;
  int t = threadIdx.x;
  int tr = t >> 4, tc4 = (t & 15) * 4;
#pragma unroll
  for (int p = 0; p < 4; ++p) {
    int row = p * 16 + tr;
    float4 v = *(const float4*)(x + (size_t)(r0 + row) * C + c0 + tc4);
    tile[row][tc4 + 0] = v.x;
    tile[row][tc4 + 1] = v.y;
    tile[row][tc4 + 2] = v.z;
    tile[row][tc4 + 3] = v.w;
    bf16x4 o = {(bf16_t)v.x, (bf16_t)v.y, (bf16_t)v.z, (bf16_t)v.w};
    *(bf16x4*)(Xb + (size_t)(r0 + row) * C + c0 + tc4) = o;
  }
  __syncthreads();
#pragma unroll
  for (int p = 0; p < 4; ++p) {
    int c = p * 16 + tr;
    bf16x4 o = {(bf16_t)tile[tc4 + 0][c], (bf16_t)tile[tc4 + 1][c],
                (bf16_t)tile[tc4 + 2][c], (bf16_t)tile[tc4 + 3][c]};
    *(bf16x4*)(XT + (size_t)(c0 + c) * R + r0 + tc4) = o;
  }
}

// ---------------------------------------------------------------------------
// mlp half-block body: one 128-row MLP sub-block run by 256 threads (t2 in
// [0,256)) out of a 512-thread block. Bs = 48KB LDS carve, sred = 256 floats.
// K=168 padded to 192, W1 staged in [kc][h] chunk layout with XOR swizzle.
// ---------------------------------------------------------------------------
__device__ __forceinline__ void mlp_half(
    int t2, int r0, bf16_t* __restrict__ Bs, float* __restrict__ sred,
    const bf16_t* __restrict__ T, const bf16_t* __restrict__ Wh,
    const float* __restrict__ b1h, const float* __restrict__ w2h, float b2v,
    float* __restrict__ out, int accumulate) {
  int lane = t2 & 63, wvh = t2 >> 6;
  int wm = wvh >> 1, wn = wvh & 1;
  int quad = lane >> 4, l15 = lane & 15;

  // zero the pad chunks [2688, 3072) = kc 21..23
  for (int c = 2688 + t2; c < 3072; c += 256) {
    int4 z = {0, 0, 0, 0};
    *(int4*)(Bs + (size_t)c * 8) = z;
  }
  // stage 2688 valid chunks; LDS pos c -> kc=c>>7, h = (c&127) ^ ((kc&3)<<2)
  for (int i = 0; i < 11; ++i) {
    int c = i * 256 + t2;
    if (c < 2688) {  // 2688 = 42 full waves: no partial-wave exec masks
      int kc = c >> 7;
      int h = (c & 127) ^ ((kc & 3) << 2);
      GLOAD_LDS16(Wh + (size_t)h * NW + kc * 8, Bs + (size_t)(i * 256 + wvh * 64) * 8);
    }
  }

  // A row pointers (per mi): row index R = r0 + wm*64 + mi*16 + l15
  const bf16_t* arow[4];
#pragma unroll
  for (int mi = 0; mi < 4; ++mi) {
    int R = r0 + wm * 64 + mi * 16 + l15;
    arow[mi] = T + (size_t)(R >> 5) * NBW + (size_t)(R & 31) * NW + quad * 8;
  }

  floatx4 zero4 = {0.f, 0.f, 0.f, 0.f};
  floatx4 acc[4][4];
#pragma unroll
  for (int mi = 0; mi < 4; ++mi)
#pragma unroll
    for (int ni = 0; ni < 4; ++ni) acc[mi][ni] = zero4;

  __syncthreads();  // staging (incl. async loads) complete (both halves)

#pragma unroll
  for (int kb = 0; kb < 192; kb += 32) {
    int kc = (kb >> 3) + quad;
    bf16x8 af[4], bf[4];
#pragma unroll
    for (int mi = 0; mi < 4; ++mi)
      af[mi] = *(const bf16x8*)(arow[mi] + kb);  // k>=168 reads garbage; B pad=0
#pragma unroll
    for (int ni = 0; ni < 4; ++ni) {
      int hpos = (wn * 64 + ni * 16 + l15) ^ ((kc & 3) << 2);
      bf[ni] = *(const bf16x8*)(Bs + (size_t)(kc * 128 + hpos) * 8);
    }
#pragma unroll
    for (int mi = 0; mi < 4; ++mi)
#pragma unroll
      for (int ni = 0; ni < 4; ++ni)
        acc[mi][ni] = __builtin_amdgcn_mfma_f32_16x16x32_bf16(af[mi], bf[ni], acc[mi][ni], 0, 0, 0);
  }

  // epilogue: relu(H + b1) dot W2 per row
  float part[4][4];
#pragma unroll
  for (int mi = 0; mi < 4; ++mi)
#pragma unroll
    for (int r = 0; r < 4; ++r) part[mi][r] = 0.f;
#pragma unroll
  for (int ni = 0; ni < 4; ++ni) {
    int col = wn * 64 + ni * 16 + l15;
    float b1v = b1h[col];
    float w2v = w2h[col];
#pragma unroll
    for (int mi = 0; mi < 4; ++mi)
#pragma unroll
      for (int r = 0; r < 4; ++r) {
        float h = acc[mi][ni][r] + b1v;
        h = h > 0.f ? h : 0.f;
        part[mi][r] += h * w2v;
      }
  }
#pragma unroll
  for (int off = 1; off < 16; off <<= 1)
#pragma unroll
    for (int mi = 0; mi < 4; ++mi)
#pragma unroll
      for (int r = 0; r < 4; ++r) part[mi][r] += __shfl_xor(part[mi][r], off);
  if (l15 == 0) {
#pragma unroll
    for (int mi = 0; mi < 4; ++mi)
#pragma unroll
      for (int r = 0; r < 4; ++r) sred[wvh * 64 + mi * 16 + quad * 4 + r] = part[mi][r];
  }
  __syncthreads();
  if (t2 < 128) {
    int hh = t2 >> 6;
    int lr = t2 & 63;
    float v = sred[(hh * 2) * 64 + lr] + sred[(hh * 2 + 1) * 64 + lr] + b2v;
    int R = r0 + hh * 64 + lr;
    int idx = (R & 31) * NM + (R >> 5);  // out[b*M + m]
    if (accumulate)
      out[idx] += v;
    else
      out[idx] = v;
  }
}

// ---------------------------------------------------------------------------
// Fused launch: blocks [0,NGEMM) run a 256x256 8-phase NT GEMM tile
// (C[m,n] = sum_k A[m,k]*Bt[n,k], epilogue also writes Ct[n][m]); blocks
// [NGEMM, NGEMM+NMLPB) each run TWO 128-row MLP sub-blocks of the PREVIOUS
// hop (independent of this launch's gemm) -- fills the 88 CUs the 168-block
// gemm grid leaves idle.
// GEMM LDS swizzle f(row) = (row>>1)&3: slot index s = 4*(row&1) + chunk
// covers all 8 16B-slots per 8 consecutive lanes (round-1's f=row&3 left a
// 2-way collision per HW 8-lane phase -> measured +8 cyc per ds_read_b128).
// ---------------------------------------------------------------------------
#define STAGE2(gbase, ld, t, ks, ldsbase)                                        \
  do {                                                                           \
    const bf16_t* _g = (gbase) + (size_t)(t) * 64 + (ks) * 32;                   \
    GLOAD_LDS16(_g, lds + (ldsbase) + (ks) * 8192 + wv * 512);                   \
    GLOAD_LDS16(_g + (size_t)128 * (ld),                                         \
                lds + (ldsbase) + (ks) * 8192 + 4096 + wv * 512);                \
  } while (0)

#define VM4 asm volatile("s_waitcnt vmcnt(4)" ::: "memory")

#define PHASE(bufoff, ks, mh, READB, STG, WAIT)                                  \
  do {                                                                           \
    if (READB) {                                                                 \
      _Pragma("unroll") for (int ni = 0; ni < 4; ++ni)                           \
          bfr[ni] = *(const bf16x8*)(pB + (bufoff) + (ks) * 8192 + ni * 512);    \
    }                                                                            \
    _Pragma("unroll") for (int mi = 0; mi < 4; ++mi)                             \
        afr[mi] =                                                                \
            *(const bf16x8*)(pA + (bufoff) + (ks) * 8192 + ((mh) * 4 + mi) * 512); \
    STG;                                                                         \
    WAIT;                                                                        \
    __builtin_amdgcn_s_barrier();                                                \
    asm volatile("s_waitcnt lgkmcnt(0)" ::: "memory");                           \
    __builtin_amdgcn_sched_barrier(0);                                           \
    __builtin_amdgcn_s_setprio(1);                                               \
    _Pragma("unroll") for (int mi = 0; mi < 4; ++mi)                             \
        _Pragma("unroll") for (int ni = 0; ni < 4; ++ni)                         \
            acc[(mh) * 4 + mi][ni] = __builtin_amdgcn_mfma_f32_16x16x32_bf16(    \
                afr[mi], bfr[ni], acc[(mh) * 4 + mi][ni], 0, 0, 0);              \
    __builtin_amdgcn_s_setprio(0);                                               \
    __builtin_amdgcn_s_barrier();                                                \
  } while (0)

__global__ __launch_bounds__(512, 2) void fused_gemm_mlp_kernel(
    const bf16_t* __restrict__ A, const bf16_t* __restrict__ Bt,
    bf16_t* __restrict__ C, bf16_t* __restrict__ Ct,
    int K, int lda, int ldb, int ldc, int ldct, int write_c,
    const bf16_t* __restrict__ T, const bf16_t* __restrict__ W1b,
    const float* __restrict__ b1, const float* __restrict__ W2,
    const float* __restrict__ b2, float* __restrict__ out,
    int hop, int accumulate) {
  __shared__ bf16_t lds[65536];  // 128 KiB union
  const int bx = blockIdx.x;
  const int tid = threadIdx.x;

  if (bx >= NGEMM) {
    // ---- MLP path: two 128-row sub-blocks (hop = previous hop) ----
    int j = bx - NGEMM;
    int h = tid >> 8;        // half 0: waves 0-3, half 1: waves 4-7
    int t2 = tid & 255;
    bf16_t* Bs = lds + (size_t)h * 24576;                 // 48KB each
    float* sred = (float*)(lds + 49152) + h * 256;        // 1KB each
    int r0 = (2 * j + h) * 128;
    mlp_half(t2, r0, Bs, sred, T, W1b + (size_t)hop * NHID * NW,
             b1 + hop * NHID, W2 + hop * NHID, b2[hop], out, accumulate);
    return;
  }

  // ---- GEMM path ----
  const int m0 = (bx >> 3) * 256, n0 = (bx & 7) * 256;
  const int lane = tid & 63, wv = tid >> 6;
  const int wm = wv >> 2, wn = wv & 3;
  const int quad = lane >> 4, l15 = lane & 15;

  // staging source (per thread): rows srow and srow+128 of the 256-row half,
  // chunk pre-swizzled with f(row)=(row>>1)&3 (same f for row+128).
  const int srow = tid >> 2;
  const int scsw = (tid & 3) ^ ((srow >> 1) & 3);
  const bf16_t* aS = A + (size_t)(m0 + srow) * lda + scsw * 8;
  const bf16_t* bS = Bt + (size_t)(n0 + srow) * ldb + scsw * 8;

  // fragment read base (elems): row*32 + swizzled chunk, f(row)=(l15>>1)&3
  const int fsw = (quad ^ ((l15 >> 1) & 3)) * 8;
  const bf16_t* pA = lds + (size_t)(wm * 128 + l15) * 32 + fsw;
  const bf16_t* pB = lds + 16384 + (size_t)(wn * 64 + l15) * 32 + fsw;

  floatx4 zero4 = {0.f, 0.f, 0.f, 0.f};
  floatx4 acc[8][4];
#pragma unroll
  for (int mi = 0; mi < 8; ++mi)
#pragma unroll
    for (int ni = 0; ni < 4; ++ni) acc[mi][ni] = zero4;

  // prologue: tile0 (all 4 halves, buf0) + tile1 ks0 (buf1)
  STAGE2(aS, lda, 0, 0, 0);
  STAGE2(bS, ldb, 0, 0, 16384);
  STAGE2(aS, lda, 0, 1, 0);
  STAGE2(bS, ldb, 0, 1, 16384);
  STAGE2(aS, lda, 1, 0, 32768);
  STAGE2(bS, ldb, 1, 0, 49152);
  VM4;
  __builtin_amdgcn_s_barrier();

  bf16x8 afr[4], bfr[4];
  const int nt = K >> 6;    // K-tiles
  const int nit = K >> 7;   // iterations (2 K-tiles each)
#pragma unroll 1
  for (int i = 0; i < nit; ++i) {
    const int t1 = 2 * i + 1;
    const int t2 = (t1 + 1 < nt) ? t1 + 1 : 0;  // clamp: keep vmcnt counts uniform
    const int t3 = (t1 + 2 < nt) ? t1 + 2 : 0;
    // phases 1-4: compute buf0 (tile 2i); phases 5-8: compute buf1 (tile 2i+1)
    PHASE(0,     0, 0, 1, STAGE2(aS, lda, t1, 1, 32768), (void)0);
    PHASE(0,     0, 1, 0, STAGE2(bS, ldb, t1, 1, 49152), (void)0);
    PHASE(0,     1, 0, 1, STAGE2(aS, lda, t2, 0, 0),     (void)0);
    PHASE(0,     1, 1, 0, STAGE2(bS, ldb, t2, 0, 16384), VM4);
    PHASE(32768, 0, 0, 1, STAGE2(aS, lda, t2, 1, 0),     (void)0);
    PHASE(32768, 0, 1, 0, STAGE2(bS, ldb, t2, 1, 16384), (void)0);
    PHASE(32768, 1, 0, 1, STAGE2(aS, lda, t3, 0, 32768), (void)0);
    PHASE(32768, 1, 1, 0, STAGE2(bS, ldb, t3, 0, 49152), VM4);
  }
  asm volatile("s_waitcnt vmcnt(0)" ::: "memory");

  // epilogue: C rows m0+wm*128+mi*16+quad*4+r, cols n0+wn*64+ni*16+l15
#pragma unroll
  for (int mi = 0; mi < 8; ++mi) {
#pragma unroll
    for (int ni = 0; ni < 4; ++ni) {
      int col = n0 + wn * 64 + ni * 16 + l15;
      int rowb = m0 + wm * 128 + mi * 16 + quad * 4;
      bf16x4 tv;
#pragma unroll
      for (int r = 0; r < 4; ++r) tv[r] = (bf16_t)acc[mi][ni][r];
      *(bf16x4*)(Ct + (size_t)col * ldct + rowb) = tv;
      if (write_c) {
#pragma unroll
        for (int r = 0; r < 4; ++r)
          C[(size_t)(rowb + r) * ldc + col] = tv[r];
      }
    }
  }
}

// Standalone MLP (hop 6 tail): original 256-thread version.
__global__ void mlp_score_kernel(const bf16_t* __restrict__ T, const bf16_t* __restrict__ W1b,
                                 const float* __restrict__ b1, const float* __restrict__ W2,
                                 const float* __restrict__ b2, float* __restrict__ out,
                                 int hop, int accumulate) {
  __shared__ bf16_t Bs[24 * 128 * 8];  // 48 KB
  __shared__ float sred[256];
  mlp_half(threadIdx.x, blockIdx.x * 128, Bs, sred, T,
           W1b + (size_t)hop * NHID * NW, b1 + hop * NHID, W2 + hop * NHID,
           b2[hop], out, accumulate);
}

extern "C" void kernel_launch(void* const* d_in, const int* in_sizes, int n_in,
                              void* d_out, int out_size, void* d_ws, size_t ws_size,
                              hipStream_t stream) {
  const float* x = (const float*)d_in[0];
  const float* L = (const float*)d_in[1];
  const float* W1 = (const float*)d_in[2];
  const float* b1 = (const float*)d_in[3];
  const float* W2 = (const float*)d_in[4];
  const float* b2 = (const float*)d_in[5];
  float* out = (float*)d_out;

  char* ws = (char*)d_ws;
  size_t off = 0;
  auto walloc = [&](size_t bytes) -> void* {
    off = (off + 255) & ~(size_t)255;
    void* p = ws + off;
    off += bytes;
    return p;
  };
  bf16_t* Xb = (bf16_t*)walloc((size_t)NBW * NM * 2);   // Tt_0 = x cast: [(b,w)][m]
  bf16_t* XT0 = (bf16_t*)walloc((size_t)NM * NBW * 2);  // [m][(b,w)] MLP input, buf 0
  bf16_t* XT1 = (bf16_t*)walloc((size_t)NM * NBW * 2);  // [m][(b,w)] MLP input, buf 1
  bf16_t* Lb = (bf16_t*)walloc((size_t)NM * NM * 2);    // L bf16 (NT B-operand)
  bf16_t* W1b = (bf16_t*)walloc((size_t)7 * NHID * NW * 2);
  bf16_t* Ta = (bf16_t*)walloc((size_t)NBW * NM * 2);   // ping-pong partner of Xb
  (void)ws_size; (void)in_sizes; (void)n_in; (void)out_size;

  prep_x_kernel<<<dim3(NM / 64, NBW / 64), dim3(256), 0, stream>>>(x, Xb, XT0);
  cast_bf16_kernel<<<dim3(1024), dim3(256), 0, stream>>>(L, Lb, NM * NM / 4);
  cast_bf16_kernel<<<dim3(64), dim3(256), 0, stream>>>(W1, W1b, 7 * NHID * NW / 4);

  // Fused chain: launch i computes gemm hop i (Tt_i + XT_i) on blocks 0-167
  // and mlp hop i-1 (reading XT_{i-1}) on blocks 168-423.
  bf16_t* src = Xb;
  bf16_t* dst = Ta;
  bf16_t* xtprev = XT0;
  bf16_t* xtcur = XT1;
  for (int i = 1; i <= 6; ++i) {
    fused_gemm_mlp_kernel<<<dim3(NGEMM + NMLPB), dim3(512), 0, stream>>>(
        src, Lb, dst, xtcur, NM, NM, NM, NM, NBW, (i < 6) ? 1 : 0,
        xtprev, W1b, b1, W2, b2, out, i - 1, (i > 1) ? 1 : 0);
    bf16_t* t = src; src = dst; dst = t;
    t = xtprev; xtprev = xtcur; xtcur = t;
  }
  // tail: mlp hop 6 on the last XT
  mlp_score_kernel<<<dim3(NM * NB / 128), dim3(256), 0, stream>>>(
      xtprev, W1b, b1, W2, b2, out, 6, 1);
}

// Round 3
// 473.584 us; speedup vs baseline: 1.2065x; 1.0186x over previous
//
#include <hip/hip_runtime.h>
#include <cstdint>
#include <cstddef>

typedef __bf16 bf16_t;
typedef __attribute__((ext_vector_type(8))) __bf16 bf16x8;
typedef __attribute__((ext_vector_type(4))) __bf16 bf16x4;
typedef __attribute__((ext_vector_type(4))) float floatx4;

#define NB 32
#define NW 168
#define NM 2048
#define NHID 128
#define NBW (NB * NW)  // 5376
#define NGEMM 168      // 21 m-tiles x 8 n-tiles of 256^2
#define NMLPB 256      // 256 fused blocks x 2 halves = 512 row-blocks of 128

#define GLOAD_LDS16(g, l)                                          \
  __builtin_amdgcn_global_load_lds(                                \
      (const __attribute__((address_space(1))) void*)(g),          \
      (__attribute__((address_space(3))) void*)(l), 16, 0, 0)

// elementwise fp32 -> bf16 cast, n4 = n/4
__global__ void cast_bf16_kernel(const float* __restrict__ in, bf16_t* __restrict__ out, int n4) {
  int stride = gridDim.x * blockDim.x;
  for (int i = blockIdx.x * blockDim.x + threadIdx.x; i < n4; i += stride) {
    float4 v = ((const float4*)in)[i];
    bf16x4 o = {(bf16_t)v.x, (bf16_t)v.y, (bf16_t)v.z, (bf16_t)v.w};
    ((bf16x4*)out)[i] = o;
  }
}

// Fused x prep: read x [(bw)][m] fp32 once; write Xb [(bw)][m] bf16 (cast) and
// XT [m][(bw)] bf16 (transpose). 64x64 tiles.
__global__ void prep_x_kernel(const float* __restrict__ x, bf16_t* __restrict__ Xb,
                              bf16_t* __restrict__ XT) {
  __shared__ float tile[64][65];
  const int R = NBW, C = NM;
  int r0 = blockIdx.y * 64, c0 = blockIdx.x * 64;
  int t = threadIdx.x;
  int tr = t >> 4, tc4 = (t & 15) * 4;
#pragma unroll
  for (int p = 0; p < 4; ++p) {
    int row = p * 16 + tr;
    float4 v = *(const float4*)(x + (size_t)(r0 + row) * C + c0 + tc4);
    tile[row][tc4 + 0] = v.x;
    tile[row][tc4 + 1] = v.y;
    tile[row][tc4 + 2] = v.z;
    tile[row][tc4 + 3] = v.w;
    bf16x4 o = {(bf16_t)v.x, (bf16_t)v.y, (bf16_t)v.z, (bf16_t)v.w};
    *(bf16x4*)(Xb + (size_t)(r0 + row) * C + c0 + tc4) = o;
  }
  __syncthreads();
#pragma unroll
  for (int p = 0; p < 4; ++p) {
    int c = p * 16 + tr;
    bf16x4 o = {(bf16_t)tile[tc4 + 0][c], (bf16_t)tile[tc4 + 1][c],
                (bf16_t)tile[tc4 + 2][c], (bf16_t)tile[tc4 + 3][c]};
    *(bf16x4*)(XT + (size_t)(c0 + c) * R + r0 + tc4) = o;
  }
}

// ---------------------------------------------------------------------------
// mlp half-block body: one 128-row MLP sub-block run by 256 threads (t2 in
// [0,256)) out of a 512-thread block. Bs = 48KB LDS carve, sred = 256 floats.
// K=168 padded to 192, W1 staged in [kc][h] chunk layout with XOR swizzle.
// ---------------------------------------------------------------------------
__device__ __forceinline__ void mlp_half(
    int t2, int r0, bf16_t* __restrict__ Bs, float* __restrict__ sred,
    const bf16_t* __restrict__ T, const bf16_t* __restrict__ Wh,
    const float* __restrict__ b1h, const float* __restrict__ w2h, float b2v,
    float* __restrict__ out, int accumulate) {
  int lane = t2 & 63, wvh = t2 >> 6;
  int wm = wvh >> 1, wn = wvh & 1;
  int quad = lane >> 4, l15 = lane & 15;

  // zero the pad chunks [2688, 3072) = kc 21..23
  for (int c = 2688 + t2; c < 3072; c += 256) {
    int4 z = {0, 0, 0, 0};
    *(int4*)(Bs + (size_t)c * 8) = z;
  }
  // stage 2688 valid chunks; LDS pos c -> kc=c>>7, h = (c&127) ^ ((kc&3)<<2)
  for (int i = 0; i < 11; ++i) {
    int c = i * 256 + t2;
    if (c < 2688) {  // 2688 = 42 full waves: no partial-wave exec masks
      int kc = c >> 7;
      int h = (c & 127) ^ ((kc & 3) << 2);
      GLOAD_LDS16(Wh + (size_t)h * NW + kc * 8, Bs + (size_t)(i * 256 + wvh * 64) * 8);
    }
  }

  // A row pointers (per mi): row index R = r0 + wm*64 + mi*16 + l15
  const bf16_t* arow[4];
#pragma unroll
  for (int mi = 0; mi < 4; ++mi) {
    int R = r0 + wm * 64 + mi * 16 + l15;
    arow[mi] = T + (size_t)(R >> 5) * NBW + (size_t)(R & 31) * NW + quad * 8;
  }

  floatx4 zero4 = {0.f, 0.f, 0.f, 0.f};
  floatx4 acc[4][4];
#pragma unroll
  for (int mi = 0; mi < 4; ++mi)
#pragma unroll
    for (int ni = 0; ni < 4; ++ni) acc[mi][ni] = zero4;

  __syncthreads();  // staging (incl. async loads) complete (both halves)

#pragma unroll
  for (int kb = 0; kb < 192; kb += 32) {
    int kc = (kb >> 3) + quad;
    bf16x8 af[4], bf[4];
#pragma unroll
    for (int mi = 0; mi < 4; ++mi)
      af[mi] = *(const bf16x8*)(arow[mi] + kb);  // k>=168 reads garbage; B pad=0
#pragma unroll
    for (int ni = 0; ni < 4; ++ni) {
      int hpos = (wn * 64 + ni * 16 + l15) ^ ((kc & 3) << 2);
      bf[ni] = *(const bf16x8*)(Bs + (size_t)(kc * 128 + hpos) * 8);
    }
#pragma unroll
    for (int mi = 0; mi < 4; ++mi)
#pragma unroll
      for (int ni = 0; ni < 4; ++ni)
        acc[mi][ni] = __builtin_amdgcn_mfma_f32_16x16x32_bf16(af[mi], bf[ni], acc[mi][ni], 0, 0, 0);
  }

  // epilogue: relu(H + b1) dot W2 per row
  float part[4][4];
#pragma unroll
  for (int mi = 0; mi < 4; ++mi)
#pragma unroll
    for (int r = 0; r < 4; ++r) part[mi][r] = 0.f;
#pragma unroll
  for (int ni = 0; ni < 4; ++ni) {
    int col = wn * 64 + ni * 16 + l15;
    float b1v = b1h[col];
    float w2v = w2h[col];
#pragma unroll
    for (int mi = 0; mi < 4; ++mi)
#pragma unroll
      for (int r = 0; r < 4; ++r) {
        float h = acc[mi][ni][r] + b1v;
        h = h > 0.f ? h : 0.f;
        part[mi][r] += h * w2v;
      }
  }
#pragma unroll
  for (int off = 1; off < 16; off <<= 1)
#pragma unroll
    for (int mi = 0; mi < 4; ++mi)
#pragma unroll
      for (int r = 0; r < 4; ++r) part[mi][r] += __shfl_xor(part[mi][r], off);
  if (l15 == 0) {
#pragma unroll
    for (int mi = 0; mi < 4; ++mi)
#pragma unroll
      for (int r = 0; r < 4; ++r) sred[wvh * 64 + mi * 16 + quad * 4 + r] = part[mi][r];
  }
  __syncthreads();
  if (t2 < 128) {
    int hh = t2 >> 6;
    int lr = t2 & 63;
    float v = sred[(hh * 2) * 64 + lr] + sred[(hh * 2 + 1) * 64 + lr] + b2v;
    int R = r0 + hh * 64 + lr;
    int idx = (R & 31) * NM + (R >> 5);  // out[b*M + m]
    if (accumulate)
      out[idx] += v;
    else
      out[idx] = v;
  }
}

// ---------------------------------------------------------------------------
// Fused launch: blocks [0,NGEMM) run a 256x256 8-phase NT GEMM tile; blocks
// [NGEMM, NGEMM+NMLPB) each run TWO 128-row MLP sub-blocks of the PREVIOUS hop.
//
// PHASE order (round-3 fix): {ds_reads; barrier; lgkmcnt(0); MFMA; STG; barrier}.
// Round-2 had STG between the ds_reads and barrier1: global_load_lds writes LDS,
// so the compiler conservatively drained lgkmcnt(0) before issuing it (WAR on
// LDS it can't disambiguate) -> every wave's reads fully drained before
// barrier1 -> reads and MFMA ran serial (measured 1105 cyc/phase ~= 576 read +
// 621 MFMA). Moving STG after the MFMAs makes the conservative wait free
// (lgkm already 0 there), restoring cross-wave read/MFMA overlap. The
// per-phase sched_barrier(0) is dropped (reads are compiler-visible; rule #18
// only applies to inline-asm ds_reads; m141 showed order-pinning regresses).
// vmcnt bookkeeping unchanged: VM4 only at phases 4 and 8 (steady-state
// in-flight enters each iteration at 4; at each VM4 the 4 newest loads are the
// two most recent STAGE2s, so the buffer about to be computed has landed).
// ---------------------------------------------------------------------------
#define STAGE2(gbase, ld, t, ks, ldsbase)                                        \
  do {                                                                           \
    const bf16_t* _g = (gbase) + (size_t)(t) * 64 + (ks) * 32;                   \
    GLOAD_LDS16(_g, lds + (ldsbase) + (ks) * 8192 + wv * 512);                   \
    GLOAD_LDS16(_g + (size_t)128 * (ld),                                         \
                lds + (ldsbase) + (ks) * 8192 + 4096 + wv * 512);                \
  } while (0)

#define VM4 asm volatile("s_waitcnt vmcnt(4)" ::: "memory")

#define PHASE(bufoff, ks, mh, READB, STG, WAIT)                                  \
  do {                                                                           \
    if (READB) {                                                                 \
      _Pragma("unroll") for (int ni = 0; ni < 4; ++ni)                           \
          bfr[ni] = *(const bf16x8*)(pB + (bufoff) + (ks) * 8192 + ni * 512);    \
    }                                                                            \
    _Pragma("unroll") for (int mi = 0; mi < 4; ++mi)                             \
        afr[mi] =                                                                \
            *(const bf16x8*)(pA + (bufoff) + (ks) * 8192 + ((mh) * 4 + mi) * 512); \
    __builtin_amdgcn_s_barrier();                                                \
    asm volatile("s_waitcnt lgkmcnt(0)" ::: "memory");                           \
    __builtin_amdgcn_s_setprio(1);                                               \
    _Pragma("unroll") for (int mi = 0; mi < 4; ++mi)                             \
        _Pragma("unroll") for (int ni = 0; ni < 4; ++ni)                         \
            acc[(mh) * 4 + mi][ni] = __builtin_amdgcn_mfma_f32_16x16x32_bf16(    \
                afr[mi], bfr[ni], acc[(mh) * 4 + mi][ni], 0, 0, 0);              \
    __builtin_amdgcn_s_setprio(0);                                               \
    STG;                                                                         \
    WAIT;                                                                        \
    __builtin_amdgcn_s_barrier();                                                \
  } while (0)

__global__ __launch_bounds__(512, 2) void fused_gemm_mlp_kernel(
    const bf16_t* __restrict__ A, const bf16_t* __restrict__ Bt,
    bf16_t* __restrict__ C, bf16_t* __restrict__ Ct,
    int K, int lda, int ldb, int ldc, int ldct, int write_c,
    const bf16_t* __restrict__ T, const bf16_t* __restrict__ W1b,
    const float* __restrict__ b1, const float* __restrict__ W2,
    const float* __restrict__ b2, float* __restrict__ out,
    int hop, int accumulate) {
  __shared__ bf16_t lds[65536];  // 128 KiB union
  const int bx = blockIdx.x;
  const int tid = threadIdx.x;

  if (bx >= NGEMM) {
    // ---- MLP path: two 128-row sub-blocks (hop = previous hop) ----
    int j = bx - NGEMM;
    int h = tid >> 8;        // half 0: waves 0-3, half 1: waves 4-7
    int t2 = tid & 255;
    bf16_t* Bs = lds + (size_t)h * 24576;                 // 48KB each
    float* sred = (float*)(lds + 49152) + h * 256;        // 1KB each
    int r0 = (2 * j + h) * 128;
    mlp_half(t2, r0, Bs, sred, T, W1b + (size_t)hop * NHID * NW,
             b1 + hop * NHID, W2 + hop * NHID, b2[hop], out, accumulate);
    return;
  }

  // ---- GEMM path ----
  const int m0 = (bx >> 3) * 256, n0 = (bx & 7) * 256;
  const int lane = tid & 63, wv = tid >> 6;
  const int wm = wv >> 2, wn = wv & 3;
  const int quad = lane >> 4, l15 = lane & 15;

  // staging source (per thread): rows srow and srow+128 of the 256-row half,
  // chunk pre-swizzled with f(row)=(row>>1)&3 (same f for row+128).
  const int srow = tid >> 2;
  const int scsw = (tid & 3) ^ ((srow >> 1) & 3);
  const bf16_t* aS = A + (size_t)(m0 + srow) * lda + scsw * 8;
  const bf16_t* bS = Bt + (size_t)(n0 + srow) * ldb + scsw * 8;

  // fragment read base (elems): row*32 + swizzled chunk, f(row)=(l15>>1)&3
  const int fsw = (quad ^ ((l15 >> 1) & 3)) * 8;
  const bf16_t* pA = lds + (size_t)(wm * 128 + l15) * 32 + fsw;
  const bf16_t* pB = lds + 16384 + (size_t)(wn * 64 + l15) * 32 + fsw;

  floatx4 zero4 = {0.f, 0.f, 0.f, 0.f};
  floatx4 acc[8][4];
#pragma unroll
  for (int mi = 0; mi < 8; ++mi)
#pragma unroll
    for (int ni = 0; ni < 4; ++ni) acc[mi][ni] = zero4;

  // prologue: tile0 (all 4 halves, buf0) + tile1 ks0 (buf1)
  STAGE2(aS, lda, 0, 0, 0);
  STAGE2(bS, ldb, 0, 0, 16384);
  STAGE2(aS, lda, 0, 1, 0);
  STAGE2(bS, ldb, 0, 1, 16384);
  STAGE2(aS, lda, 1, 0, 32768);
  STAGE2(bS, ldb, 1, 0, 49152);
  VM4;
  __builtin_amdgcn_s_barrier();

  bf16x8 afr[4], bfr[4];
  const int nt = K >> 6;    // K-tiles
  const int nit = K >> 7;   // iterations (2 K-tiles each)
#pragma unroll 1
  for (int i = 0; i < nit; ++i) {
    const int t1 = 2 * i + 1;
    const int t2 = (t1 + 1 < nt) ? t1 + 1 : 0;  // clamp: keep vmcnt counts uniform
    const int t3 = (t1 + 2 < nt) ? t1 + 2 : 0;
    // phases 1-4: compute buf0 (tile 2i); phases 5-8: compute buf1 (tile 2i+1)
    PHASE(0,     0, 0, 1, STAGE2(aS, lda, t1, 1, 32768), (void)0);
    PHASE(0,     0, 1, 0, STAGE2(bS, ldb, t1, 1, 49152), (void)0);
    PHASE(0,     1, 0, 1, STAGE2(aS, lda, t2, 0, 0),     (void)0);
    PHASE(0,     1, 1, 0, STAGE2(bS, ldb, t2, 0, 16384), VM4);
    PHASE(32768, 0, 0, 1, STAGE2(aS, lda, t2, 1, 0),     (void)0);
    PHASE(32768, 0, 1, 0, STAGE2(bS, ldb, t2, 1, 16384), (void)0);
    PHASE(32768, 1, 0, 1, STAGE2(aS, lda, t3, 0, 32768), (void)0);
    PHASE(32768, 1, 1, 0, STAGE2(bS, ldb, t3, 0, 49152), VM4);
  }
  asm volatile("s_waitcnt vmcnt(0)" ::: "memory");

  // epilogue: C rows m0+wm*128+mi*16+quad*4+r, cols n0+wn*64+ni*16+l15
#pragma unroll
  for (int mi = 0; mi < 8; ++mi) {
#pragma unroll
    for (int ni = 0; ni < 4; ++ni) {
      int col = n0 + wn * 64 + ni * 16 + l15;
      int rowb = m0 + wm * 128 + mi * 16 + quad * 4;
      bf16x4 tv;
#pragma unroll
      for (int r = 0; r < 4; ++r) tv[r] = (bf16_t)acc[mi][ni][r];
      *(bf16x4*)(Ct + (size_t)col * ldct + rowb) = tv;
      if (write_c) {
#pragma unroll
        for (int r = 0; r < 4; ++r)
          C[(size_t)(rowb + r) * ldc + col] = tv[r];
      }
    }
  }
}

// Standalone MLP (hop 6 tail): original 256-thread version.
__global__ void mlp_score_kernel(const bf16_t* __restrict__ T, const bf16_t* __restrict__ W1b,
                                 const float* __restrict__ b1, const float* __restrict__ W2,
                                 const float* __restrict__ b2, float* __restrict__ out,
                                 int hop, int accumulate) {
  __shared__ bf16_t Bs[24 * 128 * 8];  // 48 KB
  __shared__ float sred[256];
  mlp_half(threadIdx.x, blockIdx.x * 128, Bs, sred, T,
           W1b + (size_t)hop * NHID * NW, b1 + hop * NHID, W2 + hop * NHID,
           b2[hop], out, accumulate);
}

extern "C" void kernel_launch(void* const* d_in, const int* in_sizes, int n_in,
                              void* d_out, int out_size, void* d_ws, size_t ws_size,
                              hipStream_t stream) {
  const float* x = (const float*)d_in[0];
  const float* L = (const float*)d_in[1];
  const float* W1 = (const float*)d_in[2];
  const float* b1 = (const float*)d_in[3];
  const float* W2 = (const float*)d_in[4];
  const float* b2 = (const float*)d_in[5];
  float* out = (float*)d_out;

  char* ws = (char*)d_ws;
  size_t off = 0;
  auto walloc = [&](size_t bytes) -> void* {
    off = (off + 255) & ~(size_t)255;
    void* p = ws + off;
    off += bytes;
    return p;
  };
  bf16_t* Xb = (bf16_t*)walloc((size_t)NBW * NM * 2);   // Tt_0 = x cast: [(b,w)][m]
  bf16_t* XT0 = (bf16_t*)walloc((size_t)NM * NBW * 2);  // [m][(b,w)] MLP input, buf 0
  bf16_t* XT1 = (bf16_t*)walloc((size_t)NM * NBW * 2);  // [m][(b,w)] MLP input, buf 1
  bf16_t* Lb = (bf16_t*)walloc((size_t)NM * NM * 2);    // L bf16 (NT B-operand)
  bf16_t* W1b = (bf16_t*)walloc((size_t)7 * NHID * NW * 2);
  bf16_t* Ta = (bf16_t*)walloc((size_t)NBW * NM * 2);   // ping-pong partner of Xb
  (void)ws_size; (void)in_sizes; (void)n_in; (void)out_size;

  prep_x_kernel<<<dim3(NM / 64, NBW / 64), dim3(256), 0, stream>>>(x, Xb, XT0);
  cast_bf16_kernel<<<dim3(1024), dim3(256), 0, stream>>>(L, Lb, NM * NM / 4);
  cast_bf16_kernel<<<dim3(64), dim3(256), 0, stream>>>(W1, W1b, 7 * NHID * NW / 4);

  // Fused chain: launch i computes gemm hop i (Tt_i + XT_i) on blocks 0-167
  // and mlp hop i-1 (reading XT_{i-1}) on blocks 168-423.
  bf16_t* src = Xb;
  bf16_t* dst = Ta;
  bf16_t* xtprev = XT0;
  bf16_t* xtcur = XT1;
  for (int i = 1; i <= 6; ++i) {
    fused_gemm_mlp_kernel<<<dim3(NGEMM + NMLPB), dim3(512), 0, stream>>>(
        src, Lb, dst, xtcur, NM, NM, NM, NM, NBW, (i < 6) ? 1 : 0,
        xtprev, W1b, b1, W2, b2, out, i - 1, (i > 1) ? 1 : 0);
    bf16_t* t = src; src = dst; dst = t;
    t = xtprev; xtprev = xtcur; xtcur = t;
  }
  // tail: mlp hop 6 on the last XT
  mlp_score_kernel<<<dim3(NM * NB / 128), dim3(256), 0, stream>>>(
      xtprev, W1b, b1, W2, b2, out, 6, 1);
}

// Round 4
// 465.956 us; speedup vs baseline: 1.2263x; 1.0164x over previous
//
#include <hip/hip_runtime.h>
#include <cstdint>
#include <cstddef>

typedef __bf16 bf16_t;
typedef __attribute__((ext_vector_type(8))) __bf16 bf16x8;
typedef __attribute__((ext_vector_type(4))) __bf16 bf16x4;
typedef __attribute__((ext_vector_type(4))) float floatx4;

#define NB 32
#define NW 168
#define NM 2048
#define NHID 128
#define NBW (NB * NW)  // 5376
#define NGEMM 168      // 21 m-tiles x 8 n-tiles of 256^2
#define NMLPB 512      // 512 single 128-row mlp blocks

#define GLOAD_LDS16(g, l)                                          \
  __builtin_amdgcn_global_load_lds(                                \
      (const __attribute__((address_space(1))) void*)(g),          \
      (__attribute__((address_space(3))) void*)(l), 16, 0, 0)

// elementwise fp32 -> bf16 cast, n4 = n/4
__global__ void cast_bf16_kernel(const float* __restrict__ in, bf16_t* __restrict__ out, int n4) {
  int stride = gridDim.x * blockDim.x;
  for (int i = blockIdx.x * blockDim.x + threadIdx.x; i < n4; i += stride) {
    float4 v = ((const float4*)in)[i];
    bf16x4 o = {(bf16_t)v.x, (bf16_t)v.y, (bf16_t)v.z, (bf16_t)v.w};
    ((bf16x4*)out)[i] = o;
  }
}

// Fused x prep: read x [(bw)][m] fp32 once; write Xb [(bw)][m] bf16 (cast) and
// XT [m][(bw)] bf16 (transpose). 64x64 tiles.
__global__ void prep_x_kernel(const float* __restrict__ x, bf16_t* __restrict__ Xb,
                              bf16_t* __restrict__ XT) {
  __shared__ float tile[64][65];
  const int R = NBW, C = NM;
  int r0 = blockIdx.y * 64, c0 = blockIdx.x * 64;
  int t = threadIdx.x;
  int tr = t >> 4, tc4 = (t & 15) * 4;
#pragma unroll
  for (int p = 0; p < 4; ++p) {
    int row = p * 16 + tr;
    float4 v = *(const float4*)(x + (size_t)(r0 + row) * C + c0 + tc4);
    tile[row][tc4 + 0] = v.x;
    tile[row][tc4 + 1] = v.y;
    tile[row][tc4 + 2] = v.z;
    tile[row][tc4 + 3] = v.w;
    bf16x4 o = {(bf16_t)v.x, (bf16_t)v.y, (bf16_t)v.z, (bf16_t)v.w};
    *(bf16x4*)(Xb + (size_t)(r0 + row) * C + c0 + tc4) = o;
  }
  __syncthreads();
#pragma unroll
  for (int p = 0; p < 4; ++p) {
    int c = p * 16 + tr;
    bf16x4 o = {(bf16_t)tile[tc4 + 0][c], (bf16_t)tile[tc4 + 1][c],
                (bf16_t)tile[tc4 + 2][c], (bf16_t)tile[tc4 + 3][c]};
    *(bf16x4*)(XT + (size_t)(c0 + c) * R + r0 + tc4) = o;
  }
}

// ---------------------------------------------------------------------------
// mlp single-block body: one 128-row MLP sub-block. All 512 threads stage W1
// (3072 chunks = 6 per thread; pads zeroed); threads 0-255 compute; 0-127
// write out. Barriers are unconditional (no divergent-exit barriers).
// K=168 padded to 192, W1 staged in [kc][h] chunk layout with XOR swizzle.
// ---------------------------------------------------------------------------
__device__ __forceinline__ void mlp_single(
    int tid, int r0, bf16_t* __restrict__ Bs,
    const bf16_t* __restrict__ T, const bf16_t* __restrict__ Wh,
    const float* __restrict__ b1h, const float* __restrict__ w2h, float b2v,
    float* __restrict__ out, int accumulate) {
  float* sred = (float*)(Bs + 24576);  // 256 floats after the 48KB W1 tile
  int lane = tid & 63, wv2 = tid >> 6;

  // stage 3072 chunks (incl. zero pads kc 21..23): 6 per thread, wave-uniform
  // split (i=5, tid>=128 is exactly the pad range and a wave boundary).
#pragma unroll
  for (int i = 0; i < 6; ++i) {
    int c = i * 512 + tid;
    if (c >= 2688) {
      int4 z = {0, 0, 0, 0};
      *(int4*)(Bs + (size_t)c * 8) = z;
    } else {
      int kc = c >> 7;
      int h = (c & 127) ^ ((kc & 3) << 2);
      GLOAD_LDS16(Wh + (size_t)h * NW + kc * 8, Bs + (size_t)(i * 512 + wv2 * 64) * 8);
    }
  }
  __syncthreads();  // staging (incl. async loads) complete

  if (tid < 256) {
    int wm = wv2 >> 1, wn = wv2 & 1;
    int quad = lane >> 4, l15 = lane & 15;
    const bf16_t* arow[4];
#pragma unroll
    for (int mi = 0; mi < 4; ++mi) {
      int R = r0 + wm * 64 + mi * 16 + l15;
      arow[mi] = T + (size_t)(R >> 5) * NBW + (size_t)(R & 31) * NW + quad * 8;
    }
    floatx4 zero4 = {0.f, 0.f, 0.f, 0.f};
    floatx4 acc[4][4];
#pragma unroll
    for (int mi = 0; mi < 4; ++mi)
#pragma unroll
      for (int ni = 0; ni < 4; ++ni) acc[mi][ni] = zero4;

#pragma unroll
    for (int kb = 0; kb < 192; kb += 32) {
      int kc = (kb >> 3) + quad;
      bf16x8 af[4], bf[4];
#pragma unroll
      for (int mi = 0; mi < 4; ++mi)
        af[mi] = *(const bf16x8*)(arow[mi] + kb);  // k>=168 reads garbage; B pad=0
#pragma unroll
      for (int ni = 0; ni < 4; ++ni) {
        int hpos = (wn * 64 + ni * 16 + l15) ^ ((kc & 3) << 2);
        bf[ni] = *(const bf16x8*)(Bs + (size_t)(kc * 128 + hpos) * 8);
      }
#pragma unroll
      for (int mi = 0; mi < 4; ++mi)
#pragma unroll
        for (int ni = 0; ni < 4; ++ni)
          acc[mi][ni] = __builtin_amdgcn_mfma_f32_16x16x32_bf16(af[mi], bf[ni], acc[mi][ni], 0, 0, 0);
    }

    // epilogue: relu(H + b1) dot W2 per row
    float part[4][4];
#pragma unroll
    for (int mi = 0; mi < 4; ++mi)
#pragma unroll
      for (int r = 0; r < 4; ++r) part[mi][r] = 0.f;
#pragma unroll
    for (int ni = 0; ni < 4; ++ni) {
      int col = wn * 64 + ni * 16 + l15;
      float b1v = b1h[col];
      float w2v = w2h[col];
#pragma unroll
      for (int mi = 0; mi < 4; ++mi)
#pragma unroll
        for (int r = 0; r < 4; ++r) {
          float h = acc[mi][ni][r] + b1v;
          h = h > 0.f ? h : 0.f;
          part[mi][r] += h * w2v;
        }
    }
#pragma unroll
    for (int off = 1; off < 16; off <<= 1)
#pragma unroll
      for (int mi = 0; mi < 4; ++mi)
#pragma unroll
        for (int r = 0; r < 4; ++r) part[mi][r] += __shfl_xor(part[mi][r], off);
    if (l15 == 0) {
#pragma unroll
      for (int mi = 0; mi < 4; ++mi)
#pragma unroll
        for (int r = 0; r < 4; ++r) sred[wv2 * 64 + mi * 16 + quad * 4 + r] = part[mi][r];
    }
  }
  __syncthreads();
  if (tid < 128) {
    int hh = tid >> 6;
    int lr = tid & 63;
    float v = sred[(hh * 2) * 64 + lr] + sred[(hh * 2 + 1) * 64 + lr] + b2v;
    int R = r0 + hh * 64 + lr;
    int idx = (R & 31) * NM + (R >> 5);  // out[b*M + m]
    if (accumulate)
      out[idx] += v;
    else
      out[idx] = v;
  }
}

// ---------------------------------------------------------------------------
// Fused launch: blocks [0,NGEMM) run a 256x256 8-phase NT GEMM tile; blocks
// [NGEMM, NGEMM+NMLPB) run one 128-row MLP sub-block of the PREVIOUS hop.
//
// GEMM round-4 restructure: register fragment double-buffer. Phase p issues
// the ds_reads for phase p+1's fragments BEFORE the MFMA cluster of phase p
// (which consumes fragments read in p-1). The LDS pipe drains the reads while
// the matrix pipe executes the MFMAs (round-3's layout issued reads AFTER the
// previous phase's MFMAs, so in-order issue + matrix-pipe backpressure made
// reads and MFMA serial: measured 1105 cyc/phase ~= 576 read + 621 MFMA).
// No manual lgkm waits: reads are compiler-visible, hipcc emits counted
// lgkmcnt(N) before the consuming MFMAs. Sync discipline: counted vmcnt(6) +
// s_barrier at the top of EVEN phases only (the first read of each freshly
// staged region happens there; the 6 newest loads at that point are the 3
// STAGE2s issued after that region's, so VM6 drains exactly through it --
// verified for steady state, first iteration, and the clamped tail).
// ---------------------------------------------------------------------------
#define STAGE2(gbase, ld, t, ks, ldsbase)                                        \
  do {                                                                           \
    const bf16_t* _g = (gbase) + (size_t)(t) * 64 + (ks) * 32;                   \
    GLOAD_LDS16(_g, lds + (ldsbase) + (ks) * 8192 + wv * 512);                   \
    GLOAD_LDS16(_g + (size_t)128 * (ld),                                         \
                lds + (ldsbase) + (ks) * 8192 + 4096 + wv * 512);                \
  } while (0)

#define VM6 asm volatile("s_waitcnt vmcnt(6)" ::: "memory")
#define TOPB asm volatile("s_barrier" ::: "memory")
#define ENDB __builtin_amdgcn_s_barrier()

#define RD_A(dst, bufoff, ks, mh)                                                \
  _Pragma("unroll") for (int mi = 0; mi < 4; ++mi)                               \
      dst[mi] = *(const bf16x8*)(pA + (bufoff) + (ks) * 8192 + ((mh) * 4 + mi) * 512)

#define RD_B(dst, bufoff, ks)                                                    \
  _Pragma("unroll") for (int ni = 0; ni < 4; ++ni)                               \
      dst[ni] = *(const bf16x8*)(pB + (bufoff) + (ks) * 8192 + ni * 512)

#define MM16(af_, bf_, mh)                                                       \
  do {                                                                           \
    __builtin_amdgcn_s_setprio(1);                                               \
    _Pragma("unroll") for (int mi = 0; mi < 4; ++mi)                             \
        _Pragma("unroll") for (int ni = 0; ni < 4; ++ni)                         \
            acc[(mh) * 4 + mi][ni] = __builtin_amdgcn_mfma_f32_16x16x32_bf16(    \
                af_[mi], bf_[ni], acc[(mh) * 4 + mi][ni], 0, 0, 0);              \
    __builtin_amdgcn_s_setprio(0);                                               \
  } while (0)

__global__ __launch_bounds__(512, 2) void fused_gemm_mlp_kernel(
    const bf16_t* __restrict__ A, const bf16_t* __restrict__ Bt,
    bf16_t* __restrict__ C, bf16_t* __restrict__ Ct,
    int K, int lda, int ldb, int ldc, int ldct, int write_c,
    const bf16_t* __restrict__ T, const bf16_t* __restrict__ W1b,
    const float* __restrict__ b1, const float* __restrict__ W2,
    const float* __restrict__ b2, float* __restrict__ out,
    int hop, int accumulate) {
  __shared__ bf16_t lds[65536];  // 128 KiB union
  const int bx = blockIdx.x;
  const int tid = threadIdx.x;

  if (bx >= NGEMM) {
    int j = bx - NGEMM;
    mlp_single(tid, j * 128, lds, T, W1b + (size_t)hop * NHID * NW,
               b1 + hop * NHID, W2 + hop * NHID, b2[hop], out, accumulate);
    return;
  }

  // ---- GEMM path ----
  const int m0 = (bx >> 3) * 256, n0 = (bx & 7) * 256;
  const int lane = tid & 63, wv = tid >> 6;
  const int wm = wv >> 2, wn = wv & 3;
  const int quad = lane >> 4, l15 = lane & 15;

  // staging source (per thread): rows srow and srow+128 of the 256-row half,
  // chunk pre-swizzled with f(row)=(row>>1)&3 (same f for row+128).
  const int srow = tid >> 2;
  const int scsw = (tid & 3) ^ ((srow >> 1) & 3);
  const bf16_t* aS = A + (size_t)(m0 + srow) * lda + scsw * 8;
  const bf16_t* bS = Bt + (size_t)(n0 + srow) * ldb + scsw * 8;

  // fragment read base (elems): row*32 + swizzled chunk, f(row)=(l15>>1)&3
  const int fsw = (quad ^ ((l15 >> 1) & 3)) * 8;
  const bf16_t* pA = lds + (size_t)(wm * 128 + l15) * 32 + fsw;
  const bf16_t* pB = lds + 16384 + (size_t)(wn * 64 + l15) * 32 + fsw;

  floatx4 zero4 = {0.f, 0.f, 0.f, 0.f};
  floatx4 acc[8][4];
#pragma unroll
  for (int mi = 0; mi < 8; ++mi)
#pragma unroll
    for (int ni = 0; ni < 4; ++ni) acc[mi][ni] = zero4;

  // prologue: stage tile0 (buf0, both halves) + tile1 ks0 (buf1); wait for
  // tile0-ks0 (8 newer loads in flight), then pre-read phase-1's fragments.
  STAGE2(aS, lda, 0, 0, 0);
  STAGE2(bS, ldb, 0, 0, 16384);
  STAGE2(aS, lda, 0, 1, 0);
  STAGE2(bS, ldb, 0, 1, 16384);
  STAGE2(aS, lda, 1, 0, 32768);
  STAGE2(bS, ldb, 1, 0, 49152);
  asm volatile("s_waitcnt vmcnt(8)" ::: "memory");
  TOPB;

  bf16x8 af0[4], af1[4], bf0[4], bf1[4];
  RD_B(bf0, 0, 0);
  RD_A(af0, 0, 0, 0);

  const int nt = K >> 6;    // K-tiles
  const int nit = K >> 7;   // iterations (2 K-tiles each)
#pragma unroll 1
  for (int i = 0; i < nit; ++i) {
    const int t1 = 2 * i + 1;
    const int t2 = (t1 + 1 < nt) ? t1 + 1 : 0;  // clamp: keep vmcnt counts uniform
    const int t3 = (t1 + 2 < nt) ? t1 + 2 : 0;
    // p1: compute (buf0,ks0,mh0); prefetch A(buf0,ks0,mh1)
    RD_A(af1, 0, 0, 1);
    MM16(af0, bf0, 0);
    STAGE2(aS, lda, t1, 1, 32768);
    ENDB;
    // p2: compute (buf0,ks0,mh1); prefetch B+A(buf0,ks1)
    VM6; TOPB;
    RD_B(bf1, 0, 1);
    RD_A(af0, 0, 1, 0);
    MM16(af1, bf0, 1);
    STAGE2(bS, ldb, t1, 1, 49152);
    ENDB;
    // p3: compute (buf0,ks1,mh0); prefetch A(buf0,ks1,mh1)
    RD_A(af1, 0, 1, 1);
    MM16(af0, bf1, 0);
    STAGE2(aS, lda, t2, 0, 0);
    ENDB;
    // p4: compute (buf0,ks1,mh1); prefetch B+A(buf1,ks0)
    VM6; TOPB;
    RD_B(bf0, 32768, 0);
    RD_A(af0, 32768, 0, 0);
    MM16(af1, bf1, 1);
    STAGE2(bS, ldb, t2, 0, 16384);
    ENDB;
    // p5: compute (buf1,ks0,mh0); prefetch A(buf1,ks0,mh1)
    RD_A(af1, 32768, 0, 1);
    MM16(af0, bf0, 0);
    STAGE2(aS, lda, t2, 1, 0);
    ENDB;
    // p6: compute (buf1,ks0,mh1); prefetch B+A(buf1,ks1)
    VM6; TOPB;
    RD_B(bf1, 32768, 1);
    RD_A(af0, 32768, 1, 0);
    MM16(af1, bf0, 1);
    STAGE2(bS, ldb, t2, 1, 16384);
    ENDB;
    // p7: compute (buf1,ks1,mh0); prefetch A(buf1,ks1,mh1)
    RD_A(af1, 32768, 1, 1);
    MM16(af0, bf1, 0);
    STAGE2(aS, lda, t3, 0, 32768);
    ENDB;
    // p8: compute (buf1,ks1,mh1); prefetch B+A(buf0,ks0) [next iter's tile]
    VM6; TOPB;
    RD_B(bf0, 0, 0);
    RD_A(af0, 0, 0, 0);
    MM16(af1, bf1, 1);
    STAGE2(bS, ldb, t3, 0, 49152);
    ENDB;
  }
  asm volatile("s_waitcnt vmcnt(0)" ::: "memory");

  // epilogue: C rows m0+wm*128+mi*16+quad*4+r, cols n0+wn*64+ni*16+l15
#pragma unroll
  for (int mi = 0; mi < 8; ++mi) {
#pragma unroll
    for (int ni = 0; ni < 4; ++ni) {
      int col = n0 + wn * 64 + ni * 16 + l15;
      int rowb = m0 + wm * 128 + mi * 16 + quad * 4;
      bf16x4 tv;
#pragma unroll
      for (int r = 0; r < 4; ++r) tv[r] = (bf16_t)acc[mi][ni][r];
      *(bf16x4*)(Ct + (size_t)col * ldct + rowb) = tv;
      if (write_c) {
#pragma unroll
        for (int r = 0; r < 4; ++r)
          C[(size_t)(rowb + r) * ldc + col] = tv[r];
      }
    }
  }
}

// Standalone MLP (hop 6 tail): 512-thread single sub-block version.
__global__ __launch_bounds__(512) void mlp_score_kernel(
    const bf16_t* __restrict__ T, const bf16_t* __restrict__ W1b,
    const float* __restrict__ b1, const float* __restrict__ W2,
    const float* __restrict__ b2, float* __restrict__ out,
    int hop, int accumulate) {
  __shared__ bf16_t Bs[24 * 128 * 8 + 512];  // 48KB W1 tile + 1KB sred
  mlp_single(threadIdx.x, blockIdx.x * 128, Bs, T,
             W1b + (size_t)hop * NHID * NW, b1 + hop * NHID, W2 + hop * NHID,
             b2[hop], out, accumulate);
}

extern "C" void kernel_launch(void* const* d_in, const int* in_sizes, int n_in,
                              void* d_out, int out_size, void* d_ws, size_t ws_size,
                              hipStream_t stream) {
  const float* x = (const float*)d_in[0];
  const float* L = (const float*)d_in[1];
  const float* W1 = (const float*)d_in[2];
  const float* b1 = (const float*)d_in[3];
  const float* W2 = (const float*)d_in[4];
  const float* b2 = (const float*)d_in[5];
  float* out = (float*)d_out;

  char* ws = (char*)d_ws;
  size_t off = 0;
  auto walloc = [&](size_t bytes) -> void* {
    off = (off + 255) & ~(size_t)255;
    void* p = ws + off;
    off += bytes;
    return p;
  };
  bf16_t* Xb = (bf16_t*)walloc((size_t)NBW * NM * 2);   // Tt_0 = x cast: [(b,w)][m]
  bf16_t* XT0 = (bf16_t*)walloc((size_t)NM * NBW * 2);  // [m][(b,w)] MLP input, buf 0
  bf16_t* XT1 = (bf16_t*)walloc((size_t)NM * NBW * 2);  // [m][(b,w)] MLP input, buf 1
  bf16_t* Lb = (bf16_t*)walloc((size_t)NM * NM * 2);    // L bf16 (NT B-operand)
  bf16_t* W1b = (bf16_t*)walloc((size_t)7 * NHID * NW * 2);
  bf16_t* Ta = (bf16_t*)walloc((size_t)NBW * NM * 2);   // ping-pong partner of Xb
  (void)ws_size; (void)in_sizes; (void)n_in; (void)out_size;

  prep_x_kernel<<<dim3(NM / 64, NBW / 64), dim3(256), 0, stream>>>(x, Xb, XT0);
  cast_bf16_kernel<<<dim3(1024), dim3(256), 0, stream>>>(L, Lb, NM * NM / 4);
  cast_bf16_kernel<<<dim3(64), dim3(256), 0, stream>>>(W1, W1b, 7 * NHID * NW / 4);

  // Fused chain: launch i computes gemm hop i (Tt_i + XT_i) on blocks 0-167
  // and mlp hop i-1 (reading XT_{i-1}) on blocks 168-679.
  bf16_t* src = Xb;
  bf16_t* dst = Ta;
  bf16_t* xtprev = XT0;
  bf16_t* xtcur = XT1;
  for (int i = 1; i <= 6; ++i) {
    fused_gemm_mlp_kernel<<<dim3(NGEMM + NMLPB), dim3(512), 0, stream>>>(
        src, Lb, dst, xtcur, NM, NM, NM, NM, NBW, (i < 6) ? 1 : 0,
        xtprev, W1b, b1, W2, b2, out, i - 1, (i > 1) ? 1 : 0);
    bf16_t* t = src; src = dst; dst = t;
    t = xtprev; xtprev = xtcur; xtcur = t;
  }
  // tail: mlp hop 6 on the last XT
  mlp_score_kernel<<<dim3(NM * NB / 128), dim3(512), 0, stream>>>(
      xtprev, W1b, b1, W2, b2, out, 6, 1);
}